// Round 6
// baseline (317.577 us; speedup 1.0000x reference)
//
#include <hip/hip_runtime.h>

// RowLSTM v6: two-kernel split, rcp-based activations, packed (f,p) plane,
// software-pipelined scan.
//  K1 gates_k: f16-MFMA causal conv -> fp-plane [B,H,W,Hc,2] (f,p packed dword)
//              + o-plane [B,H,W,Hc] f16, both in d_ws.
//  K2 scan_k : width-serial LSTM scan, one wave per (b,h) row, lane = hc.
//   x: [B=16, C=64, H=128, W=128] fp32; conv_w: [O=256, C=64, kH=3]; conv_b: [256]
//   out: [B, Hc=64, H, W] fp32

#define NB   16
#define NC   64
#define NH   128
#define NW   128
#define NHC  64
#define NK   192
#define NPLN (NB * NH * NW * NHC)   // 16,777,216 elems / half-plane

typedef _Float16 half4 __attribute__((ext_vector_type(4)));
typedef _Float16 half8 __attribute__((ext_vector_type(8)));
typedef float    f32x4 __attribute__((ext_vector_type(4)));

__device__ __forceinline__ float frcp(float x)  { return __builtin_amdgcn_rcpf(x); }
__device__ __forceinline__ float fsig(float x)  { return frcp(1.f + __expf(-x)); }
__device__ __forceinline__ float ftanh(float x) { return 1.f - 2.f * frcp(__expf(2.f * x) + 1.f); }

// ================= K1: conv gates =================
// Fragment-order LDS: element (k,w) at plane ni=w>>4, kt=k>>5,
// row L = ((k&31)>>3)*16 + (w&15), byte j = k&7. ds_read_b128 at [lane] is the
// exact 16x16x32 B-fragment (mapping verified by v2..v5 passes).
#define NIP 3088   // halfs per ni plane (6*64*8 + 16 pad)

__global__ __launch_bounds__(256, 3) void gates_k(
    const float* __restrict__ x,
    const float* __restrict__ wgt,
    const float* __restrict__ bias,
    uint32_t*  __restrict__ fppl,     // (f,p) packed as 2 halfs per dword
    _Float16*  __restrict__ opl)
{
    __shared__ _Float16 xsf[8 * NIP];   // 49.4 KB

    const int tid  = threadIdx.x;
    const int cg   = tid >> 6;
    const int lane = tid & 63;
    const int l15  = lane & 15;
    const int l4   = lane >> 4;

    int bid = blockIdx.x;                       // XCD swizzle (2048 % 8 == 0)
    bid = (bid & 7) * (NB * NH / 8) + (bid >> 3);
    const int b = bid >> 7;
    const int h = bid & (NH - 1);

    const float* xb = x + (size_t)b * NC * NH * NW;

    // A fragments: W[o = g*64 + cg*16 + l15][k = kt*32 + l4*8 + j]
    half8 afrag[4][6];
    #pragma unroll
    for (int g = 0; g < 4; ++g) {
        const float* wo = wgt + (size_t)(g * 64 + cg * 16 + l15) * NK;
        #pragma unroll
        for (int kt = 0; kt < 6; ++kt) {
            const float4 v0 = *(const float4*)(wo + kt * 32 + l4 * 8);
            const float4 v1 = *(const float4*)(wo + kt * 32 + l4 * 8 + 4);
            half8 a;
            a[0] = (_Float16)v0.x; a[1] = (_Float16)v0.y;
            a[2] = (_Float16)v0.z; a[3] = (_Float16)v0.w;
            a[4] = (_Float16)v1.x; a[5] = (_Float16)v1.y;
            a[6] = (_Float16)v1.z; a[7] = (_Float16)v1.w;
            afrag[g][kt] = a;
        }
    }
    float bfr[4][4];
    #pragma unroll
    for (int g = 0; g < 4; ++g)
        #pragma unroll
        for (int j = 0; j < 4; ++j)
            bfr[g][j] = bias[g * 64 + cg * 16 + l4 * 4 + j];

    // ---- stage full row (192 k x 128 w) as 4k x 4w tiles: 6 tiles/thread ----
    for (int t = tid; t < 1536; t += 256) {
        const int kq  = t >> 5;          // 0..47
        const int wq  = t & 31;          // 0..31
        const int k0  = kq * 4;
        const int w0g = wq * 4;
        float4 v[4];
        #pragma unroll
        for (int dk = 0; dk < 4; ++dk) {
            const int k  = k0 + dk;
            const int c  = k / 3;
            const int kh = k - 3 * c;
            const int r  = h - 2 + kh;
            v[dk] = (r >= 0) ? *(const float4*)(xb + ((size_t)c * NH + r) * NW + w0g)
                             : make_float4(0.f, 0.f, 0.f, 0.f);
        }
        const int kt = k0 >> 5;
        const int j0 = k0 & 7;           // 0 or 4
        #pragma unroll
        for (int dw = 0; dw < 4; ++dw) {
            const int w  = w0g + dw;
            const int ni = w >> 4;
            const int L  = ((k0 & 31) >> 3) * 16 + (w & 15);
            half4 hv;
            hv[0] = (_Float16)(&v[0].x)[dw];
            hv[1] = (_Float16)(&v[1].x)[dw];
            hv[2] = (_Float16)(&v[2].x)[dw];
            hv[3] = (_Float16)(&v[3].x)[dw];
            *(half4*)&xsf[ni * NIP + kt * 512 + L * 8 + j0] = hv;
        }
    }
    __syncthreads();

    // ---- 4 passes of 2 ni each: MFMA + activation + plane stores ----
    #pragma unroll
    for (int pr = 0; pr < 4; ++pr) {
        f32x4 acc[4][2];
        #pragma unroll
        for (int g = 0; g < 4; ++g) {
            acc[g][0] = (f32x4){0.f, 0.f, 0.f, 0.f};
            acc[g][1] = (f32x4){0.f, 0.f, 0.f, 0.f};
        }
        #pragma unroll
        for (int kt = 0; kt < 6; ++kt) {
            const half8 b0 = *(const half8*)&xsf[(pr * 2 + 0) * NIP + kt * 512 + lane * 8];
            const half8 b1 = *(const half8*)&xsf[(pr * 2 + 1) * NIP + kt * 512 + lane * 8];
            #pragma unroll
            for (int g = 0; g < 4; ++g) {
                acc[g][0] = __builtin_amdgcn_mfma_f32_16x16x32_f16(afrag[g][kt], b0, acc[g][0], 0, 0, 0);
                acc[g][1] = __builtin_amdgcn_mfma_f32_16x16x32_f16(afrag[g][kt], b1, acc[g][1], 0, 0, 0);
            }
        }
        #pragma unroll
        for (int q = 0; q < 2; ++q) {
            const int w   = (pr * 2 + q) * 16 + l15;
            const int hc0 = cg * 16 + l4 * 4;
            uint32_t fp4[4];
            half4 o4;
            #pragma unroll
            for (int j = 0; j < 4; ++j) {
                const float iv = fsig (acc[0][q][j] + bfr[0][j]);
                const float fv = fsig (acc[1][q][j] + bfr[1][j]);
                const float ov = fsig (acc[2][q][j] + bfr[2][j]);
                const float gv = ftanh(acc[3][q][j] + bfr[3][j]);
                union { _Float16 h[2]; uint32_t u; } pk;
                pk.h[0] = (_Float16)fv;
                pk.h[1] = (_Float16)(iv * gv);
                fp4[j] = pk.u;
                o4[j]  = (_Float16)ov;
            }
            const size_t eb = ((size_t)(b * NH + h) * NW + w) * NHC + hc0; // elem idx
            *(uint4*)(fppl + eb) = make_uint4(fp4[0], fp4[1], fp4[2], fp4[3]);
            *(half4*)(opl  + eb) = o4;
        }
    }
}

// ================= K2: LSTM scan =================
// 4 waves/block, wave = one (b,h) row, lane = hc. Software-pipelined loads
// (named A/B buffers, all-static indices), LDS bounce for coalesced stores.
__global__ __launch_bounds__(256) void scan_k(
    const uint32_t* __restrict__ fppl,
    const _Float16* __restrict__ opl,
    float* __restrict__ out)
{
    __shared__ float hbuf[4][NHC][34];   // stride 34: float2-aligned, <=4-way writes

    const int tid  = threadIdx.x;
    const int wv   = tid >> 6;
    const int lane = tid & 63;
    const int row  = blockIdx.x * 4 + wv;
    const int b    = row >> 7;
    const int h    = row & (NH - 1);

    const size_t base = ((size_t)(b * NH + h) * NW) * NHC + lane;
    const uint32_t* fpp = fppl + base;
    const _Float16* opp = opl  + base;
    float* outb = out + (size_t)b * NHC * NH * NW;
    float* hrow = &hbuf[wv][lane][0];

    uint32_t fA[16], fB[16];
    _Float16 oA[16], oB[16];

#define LOAD16(FP, OV, W0)                                     \
    _Pragma("unroll")                                          \
    for (int s = 0; s < 16; ++s) {                             \
        FP[s] = fpp[(size_t)((W0) + s) * NHC];                 \
        OV[s] = opp[(size_t)((W0) + s) * NHC];                 \
    }

#define STEP(FPV, OV, WIDX) {                                  \
        union { uint32_t u; _Float16 hh[2]; } pk; pk.u = (FPV);\
        const float fv = (float)pk.hh[0];                      \
        const float pv = (float)pk.hh[1];                      \
        cst = fmaf(fv, cst, pv);                               \
        hrow[WIDX] = (float)(OV) * ftanh(cst); }

    float cst = 0.f;
    LOAD16(fA, oA, 0);

    #pragma unroll
    for (int pair = 0; pair < 4; ++pair) {
        const int w0 = pair * 32;
        LOAD16(fB, oB, w0 + 16);
        #pragma unroll
        for (int s = 0; s < 16; ++s) STEP(fA[s], oA[s], s);
        if (pair < 3) { LOAD16(fA, oA, w0 + 32); }
        #pragma unroll
        for (int s = 0; s < 16; ++s) STEP(fB[s], oB[s], 16 + s);

        // flush 32 w: float2 per lane, 4 hc-rows x 32 w per instr (wave-private, no barrier)
        #pragma unroll
        for (int it = 0; it < 16; ++it) {
            const int hc = it * 4 + (lane >> 4);
            const int wl = (lane & 15) * 2;
            const float2 v = *(const float2*)&hbuf[wv][hc][wl];
            *(float2*)(outb + ((size_t)hc * NH + h) * NW + w0 + wl) = v;
        }
    }
#undef LOAD16
#undef STEP
}

// ================= fallback (v3b fused, known-pass) =================
#define WC 32
#define GP (WC + 2)
#define NQ (48 * WC)
__device__ __forceinline__ void stage_chunk_fb(const float* __restrict__ xb, int h, int w0,
                                               _Float16 (*xsf)[6][64][8], int qstart, int qstep) {
    for (int q = qstart; q < NQ; q += qstep) {
        const int k4 = q >> 5; const int w = q & 31;
        const int ni = w >> 4; const int kt = k4 >> 3;
        const int L = ((k4 >> 1) & 3) * 16 + (w & 15);
        const int j0 = (k4 & 1) * 4;
        half4 hv;
        #pragma unroll
        for (int e = 0; e < 4; ++e) {
            const int k = k4 * 4 + e; const int c = k / 3;
            const int kh = k - 3 * c; const int r = h - 2 + kh;
            float v = 0.f;
            if (r >= 0) v = xb[((size_t)c * NH + r) * NW + w0 + w];
            hv[e] = (_Float16)v;
        }
        *(half4*)&xsf[ni][kt][L][j0] = hv;
    }
}
__global__ __launch_bounds__(256, 2) void rowlstm_fb(
    const float* __restrict__ x, const float* __restrict__ wgt,
    const float* __restrict__ bias, float* __restrict__ out)
{
    __shared__ _Float16 xsf[2][6][64][8];
    __shared__ float fbuf[NHC][GP]; __shared__ float pbuf[NHC][GP]; __shared__ float obuf[NHC][GP];
    const int tid = threadIdx.x; const int cg = tid >> 6;
    const int lane = tid & 63; const int l15 = lane & 15; const int l4 = lane >> 4;
    int bid = blockIdx.x; bid = (bid & 7) * (NB * NH / 8) + (bid >> 3);
    const int b = bid >> 7; const int h = bid & (NH - 1);
    const float* xb = x + (size_t)b * NC * NH * NW;
    half8 afrag[4][6];
    #pragma unroll
    for (int g = 0; g < 4; ++g) {
        const float* wo = wgt + (size_t)(g * 64 + cg * 16 + l15) * NK;
        #pragma unroll
        for (int kt = 0; kt < 6; ++kt) {
            const float4 v0 = *(const float4*)(wo + kt * 32 + l4 * 8);
            const float4 v1 = *(const float4*)(wo + kt * 32 + l4 * 8 + 4);
            half8 a;
            a[0]=(_Float16)v0.x;a[1]=(_Float16)v0.y;a[2]=(_Float16)v0.z;a[3]=(_Float16)v0.w;
            a[4]=(_Float16)v1.x;a[5]=(_Float16)v1.y;a[6]=(_Float16)v1.z;a[7]=(_Float16)v1.w;
            afrag[g][kt] = a;
        }
    }
    float bfr[4][4];
    #pragma unroll
    for (int g = 0; g < 4; ++g)
        #pragma unroll
        for (int j = 0; j < 4; ++j) bfr[g][j] = bias[g * 64 + cg * 16 + l4 * 4 + j];
    float cstate = 0.f;
    float* outrow = out + (((size_t)b * NHC + tid) * NH + h) * NW;
    stage_chunk_fb(xb, h, 0, xsf, tid, 256);
    __syncthreads();
    for (int ck = 0; ck < 4; ++ck) {
        const int w0 = ck * WC;
        f32x4 acc[4][2];
        #pragma unroll
        for (int g = 0; g < 4; ++g) { acc[g][0]=(f32x4){0,0,0,0}; acc[g][1]=(f32x4){0,0,0,0}; }
        #pragma unroll
        for (int kt = 0; kt < 6; ++kt) {
            const half8 b0 = *(const half8*)&xsf[0][kt][lane][0];
            const half8 b1 = *(const half8*)&xsf[1][kt][lane][0];
            #pragma unroll
            for (int g = 0; g < 4; ++g) {
                acc[g][0] = __builtin_amdgcn_mfma_f32_16x16x32_f16(afrag[g][kt], b0, acc[g][0], 0, 0, 0);
                acc[g][1] = __builtin_amdgcn_mfma_f32_16x16x32_f16(afrag[g][kt], b1, acc[g][1], 0, 0, 0);
            }
        }
        #pragma unroll
        for (int ni = 0; ni < 2; ++ni)
            #pragma unroll
            for (int j = 0; j < 4; ++j) {
                const float iv = fsig (acc[0][ni][j] + bfr[0][j]);
                const float fv = fsig (acc[1][ni][j] + bfr[1][j]);
                const float ov = fsig (acc[2][ni][j] + bfr[2][j]);
                const float gv = ftanh(acc[3][ni][j] + bfr[3][j]);
                const int hcr = cg * 16 + l4 * 4 + j; const int wcl = ni * 16 + l15;
                fbuf[hcr][wcl] = fv; pbuf[hcr][wcl] = iv * gv; obuf[hcr][wcl] = ov;
            }
        __syncthreads();
        if (tid < 64) {
            float c = cstate;
            #pragma unroll
            for (int w = 0; w < WC; w += 4) {
                float4 hv;
                #pragma unroll
                for (int e = 0; e < 4; ++e) {
                    c = fmaf(fbuf[tid][w + e], c, pbuf[tid][w + e]);
                    (&hv.x)[e] = obuf[tid][w + e] * ftanh(c);
                }
                *(float4*)(outrow + w0 + w) = hv;
            }
            cstate = c;
        } else if (ck < 3) stage_chunk_fb(xb, h, w0 + WC, xsf, tid - 64, 192);
        __syncthreads();
    }
}

extern "C" void kernel_launch(void* const* d_in, const int* in_sizes, int n_in,
                              void* d_out, int out_size, void* d_ws, size_t ws_size,
                              hipStream_t stream) {
    const float* x    = (const float*)d_in[0];
    const float* wgt  = (const float*)d_in[1];
    const float* bias = (const float*)d_in[2];
    float* out = (float*)d_out;

    if (ws_size >= (size_t)3 * NPLN * sizeof(_Float16)) {
        uint32_t* fppl = (uint32_t*)d_ws;                       // NPLN dwords (64 MB)
        _Float16* opl  = (_Float16*)d_ws + (size_t)2 * NPLN;    // NPLN halfs (32 MB)
        gates_k<<<NB * NH, 256, 0, stream>>>(x, wgt, bias, fppl, opl);
        scan_k<<<NB * NH / 4, 256, 0, stream>>>(fppl, opl, out);
    } else {
        rowlstm_fb<<<NB * NH, 256, 0, stream>>>(x, wgt, bias, out);
    }
}

// Round 8
// 262.317 us; speedup vs baseline: 1.2107x; 1.2107x over previous
//
#include <hip/hip_runtime.h>

// RowLSTM v7 = v5 (best measured: 255us) + ONE change: rcp-based activations
// (v_rcp_f32 replaces IEEE divide, ~12 VALU ops -> 1) in both kernels.
// Memory layout, launch bounds, store/load patterns: identical to v5.
//  K1 gates_k: f16-MFMA causal conv -> activated gate planes f,p,o (f16) in d_ws.
//  K2 scan_k : width-serial LSTM scan, one wave per (b,h) row, lane = hc.
//   x: [B=16, C=64, H=128, W=128] fp32; conv_w: [O=256, C=64, kH=3]; conv_b: [256]
//   out: [B, Hc=64, H, W] fp32
// Gate planes layout: [B, H, W, Hc] f16.

#define NB   16
#define NC   64
#define NH   128
#define NW   128
#define NHC  64
#define NK   192
#define NPLN (NB * NH * NW * NHC)   // 16,777,216 elems / plane (32 MB f16)

typedef _Float16 half4 __attribute__((ext_vector_type(4)));
typedef _Float16 half8 __attribute__((ext_vector_type(8)));
typedef float    f32x4 __attribute__((ext_vector_type(4)));

__device__ __forceinline__ float frcp(float x)  { return __builtin_amdgcn_rcpf(x); }
__device__ __forceinline__ float fsig(float x)  { return frcp(1.f + __expf(-x)); }
__device__ __forceinline__ float ftanh(float x) { return 1.f - 2.f * frcp(__expf(2.f * x) + 1.f); }

// ================= K1: conv gates =================
// Fragment-order LDS: element (k,w) at plane ni=w>>4, kt=k>>5,
// row L = ((k&31)>>3)*16 + (w&15), byte j = k&7. ds_read_b128 at [lane] is the
// exact 16x16x32 B-fragment (mapping HW-verified by v2..v5 passes).
#define NIP 3088   // halfs per ni plane: 6*64*8 + 16 pad (bank-skews the 8 planes)

__global__ __launch_bounds__(256, 2) void gates_k(
    const float* __restrict__ x,
    const float* __restrict__ wgt,
    const float* __restrict__ bias,
    _Float16* __restrict__ fpl,
    _Float16* __restrict__ ppl,
    _Float16* __restrict__ opl)
{
    __shared__ _Float16 xsf[8 * NIP];   // 49.4 KB

    const int tid  = threadIdx.x;
    const int cg   = tid >> 6;
    const int lane = tid & 63;
    const int l15  = lane & 15;
    const int l4   = lane >> 4;

    int bid = blockIdx.x;                       // XCD swizzle (2048 % 8 == 0)
    bid = (bid & 7) * (NB * NH / 8) + (bid >> 3);
    const int b = bid >> 7;
    const int h = bid & (NH - 1);

    const float* xb = x + (size_t)b * NC * NH * NW;

    // A fragments: W[o = g*64 + cg*16 + l15][k = kt*32 + l4*8 + j]
    half8 afrag[4][6];
    #pragma unroll
    for (int g = 0; g < 4; ++g) {
        const float* wo = wgt + (size_t)(g * 64 + cg * 16 + l15) * NK;
        #pragma unroll
        for (int kt = 0; kt < 6; ++kt) {
            const float4 v0 = *(const float4*)(wo + kt * 32 + l4 * 8);
            const float4 v1 = *(const float4*)(wo + kt * 32 + l4 * 8 + 4);
            half8 a;
            a[0] = (_Float16)v0.x; a[1] = (_Float16)v0.y;
            a[2] = (_Float16)v0.z; a[3] = (_Float16)v0.w;
            a[4] = (_Float16)v1.x; a[5] = (_Float16)v1.y;
            a[6] = (_Float16)v1.z; a[7] = (_Float16)v1.w;
            afrag[g][kt] = a;
        }
    }
    float bfr[4][4];
    #pragma unroll
    for (int g = 0; g < 4; ++g)
        #pragma unroll
        for (int j = 0; j < 4; ++j)
            bfr[g][j] = bias[g * 64 + cg * 16 + l4 * 4 + j];

    // ---- stage full row (192 k x 128 w) as 4k x 4w tiles: 6 tiles/thread ----
    // loads: float4 over w (contiguous 512B across 32 lanes); writes: half4 over k.
    for (int t = tid; t < 1536; t += 256) {
        const int kq  = t >> 5;          // 0..47
        const int wq  = t & 31;          // 0..31
        const int k0  = kq * 4;
        const int w0g = wq * 4;
        float4 v[4];
        #pragma unroll
        for (int dk = 0; dk < 4; ++dk) {
            const int k  = k0 + dk;
            const int c  = k / 3;
            const int kh = k - 3 * c;
            const int r  = h - 2 + kh;
            v[dk] = (r >= 0) ? *(const float4*)(xb + ((size_t)c * NH + r) * NW + w0g)
                             : make_float4(0.f, 0.f, 0.f, 0.f);
        }
        const int kt = k0 >> 5;
        const int j0 = k0 & 7;           // 0 or 4
        #pragma unroll
        for (int dw = 0; dw < 4; ++dw) {
            const int w  = w0g + dw;
            const int ni = w >> 4;
            const int L  = ((k0 & 31) >> 3) * 16 + (w & 15);
            half4 hv;
            hv[0] = (_Float16)(&v[0].x)[dw];
            hv[1] = (_Float16)(&v[1].x)[dw];
            hv[2] = (_Float16)(&v[2].x)[dw];
            hv[3] = (_Float16)(&v[3].x)[dw];
            *(half4*)&xsf[ni * NIP + kt * 512 + L * 8 + j0] = hv;
        }
    }
    __syncthreads();

    // ---- 4 passes of 2 ni each: MFMA + activation + f16 plane stores ----
    #pragma unroll
    for (int pr = 0; pr < 4; ++pr) {
        f32x4 acc[4][2];
        #pragma unroll
        for (int g = 0; g < 4; ++g) {
            acc[g][0] = (f32x4){0.f, 0.f, 0.f, 0.f};
            acc[g][1] = (f32x4){0.f, 0.f, 0.f, 0.f};
        }
        #pragma unroll
        for (int kt = 0; kt < 6; ++kt) {
            const half8 b0 = *(const half8*)&xsf[(pr * 2 + 0) * NIP + kt * 512 + lane * 8];
            const half8 b1 = *(const half8*)&xsf[(pr * 2 + 1) * NIP + kt * 512 + lane * 8];
            #pragma unroll
            for (int g = 0; g < 4; ++g) {
                acc[g][0] = __builtin_amdgcn_mfma_f32_16x16x32_f16(afrag[g][kt], b0, acc[g][0], 0, 0, 0);
                acc[g][1] = __builtin_amdgcn_mfma_f32_16x16x32_f16(afrag[g][kt], b1, acc[g][1], 0, 0, 0);
            }
        }
        #pragma unroll
        for (int q = 0; q < 2; ++q) {
            const int w   = (pr * 2 + q) * 16 + l15;
            const int hc0 = cg * 16 + l4 * 4;
            half4 f4, p4, o4;
            #pragma unroll
            for (int j = 0; j < 4; ++j) {
                const float iv = fsig (acc[0][q][j] + bfr[0][j]);
                const float fv = fsig (acc[1][q][j] + bfr[1][j]);
                const float ov = fsig (acc[2][q][j] + bfr[2][j]);
                const float gv = ftanh(acc[3][q][j] + bfr[3][j]);
                f4[j] = (_Float16)fv;
                p4[j] = (_Float16)(iv * gv);
                o4[j] = (_Float16)ov;
            }
            const size_t sb = (((size_t)(b * NH + h) * NW) + w) * NHC + hc0;
            *(half4*)(fpl + sb) = f4;
            *(half4*)(ppl + sb) = p4;
            *(half4*)(opl + sb) = o4;
        }
    }
}

// ================= K2: LSTM scan =================
// 4 waves/block, wave = one (b,h) row, lane = hc. No barriers (wave-private LDS).
__global__ __launch_bounds__(256) void scan_k(
    const _Float16* __restrict__ fpl,
    const _Float16* __restrict__ ppl,
    const _Float16* __restrict__ opl,
    float* __restrict__ out)
{
    __shared__ float hbuf[4][NHC][33];   // pad 33: scan writes (lane+s)%32 2-way free

    const int tid  = threadIdx.x;
    const int wv   = tid >> 6;
    const int lane = tid & 63;
    const int row  = blockIdx.x * 4 + wv;
    const int b    = row >> 7;
    const int h    = row & (NH - 1);

    const size_t gbase = ((size_t)(b * NH + h) * NW) * NHC + lane;
    float c = 0.f;

    for (int ck = 0; ck < 4; ++ck) {
        const size_t p0 = gbase + (size_t)ck * 32 * NHC;
        #pragma unroll
        for (int s = 0; s < 32; ++s) {
            const size_t ix = p0 + (size_t)s * NHC;
            const float f = (float)fpl[ix];
            const float p = (float)ppl[ix];
            const float o = (float)opl[ix];
            c = fmaf(f, c, p);
            hbuf[wv][lane][s] = o * ftanh(c);
        }
        // flush: 32 coalesced dword stores (2 hc-rows x 32 w per instr)
        const int wl = lane & 31;
        const int hq = lane >> 5;
        #pragma unroll
        for (int it = 0; it < 32; ++it) {
            const int hc = it * 2 + hq;
            out[(((size_t)b * NHC + hc) * NH + h) * NW + ck * 32 + wl] = hbuf[wv][hc][wl];
        }
    }
}

// ================= fallback (v3b fused, known-pass) =================
#define WC 32
#define GP (WC + 2)
#define NQ (48 * WC)
__device__ __forceinline__ void stage_chunk_fb(const float* __restrict__ xb, int h, int w0,
                                               _Float16 (*xsf)[6][64][8], int qstart, int qstep) {
    for (int q = qstart; q < NQ; q += qstep) {
        const int k4 = q >> 5; const int w = q & 31;
        const int ni = w >> 4; const int kt = k4 >> 3;
        const int L = ((k4 >> 1) & 3) * 16 + (w & 15);
        const int j0 = (k4 & 1) * 4;
        half4 hv;
        #pragma unroll
        for (int e = 0; e < 4; ++e) {
            const int k = k4 * 4 + e; const int c = k / 3;
            const int kh = k - 3 * c; const int r = h - 2 + kh;
            float v = 0.f;
            if (r >= 0) v = xb[((size_t)c * NH + r) * NW + w0 + w];
            hv[e] = (_Float16)v;
        }
        *(half4*)&xsf[ni][kt][L][j0] = hv;
    }
}
__global__ __launch_bounds__(256, 2) void rowlstm_fb(
    const float* __restrict__ x, const float* __restrict__ wgt,
    const float* __restrict__ bias, float* __restrict__ out)
{
    __shared__ _Float16 xsf[2][6][64][8];
    __shared__ float fbuf[NHC][GP]; __shared__ float pbuf[NHC][GP]; __shared__ float obuf[NHC][GP];
    const int tid = threadIdx.x; const int cg = tid >> 6;
    const int lane = tid & 63; const int l15 = lane & 15; const int l4 = lane >> 4;
    int bid = blockIdx.x; bid = (bid & 7) * (NB * NH / 8) + (bid >> 3);
    const int b = bid >> 7; const int h = bid & (NH - 1);
    const float* xb = x + (size_t)b * NC * NH * NW;
    half8 afrag[4][6];
    #pragma unroll
    for (int g = 0; g < 4; ++g) {
        const float* wo = wgt + (size_t)(g * 64 + cg * 16 + l15) * NK;
        #pragma unroll
        for (int kt = 0; kt < 6; ++kt) {
            const float4 v0 = *(const float4*)(wo + kt * 32 + l4 * 8);
            const float4 v1 = *(const float4*)(wo + kt * 32 + l4 * 8 + 4);
            half8 a;
            a[0]=(_Float16)v0.x;a[1]=(_Float16)v0.y;a[2]=(_Float16)v0.z;a[3]=(_Float16)v0.w;
            a[4]=(_Float16)v1.x;a[5]=(_Float16)v1.y;a[6]=(_Float16)v1.z;a[7]=(_Float16)v1.w;
            afrag[g][kt] = a;
        }
    }
    float bfr[4][4];
    #pragma unroll
    for (int g = 0; g < 4; ++g)
        #pragma unroll
        for (int j = 0; j < 4; ++j) bfr[g][j] = bias[g * 64 + cg * 16 + l4 * 4 + j];
    float cstate = 0.f;
    float* outrow = out + (((size_t)b * NHC + tid) * NH + h) * NW;
    stage_chunk_fb(xb, h, 0, xsf, tid, 256);
    __syncthreads();
    for (int ck = 0; ck < 4; ++ck) {
        const int w0 = ck * WC;
        f32x4 acc[4][2];
        #pragma unroll
        for (int g = 0; g < 4; ++g) { acc[g][0]=(f32x4){0,0,0,0}; acc[g][1]=(f32x4){0,0,0,0}; }
        #pragma unroll
        for (int kt = 0; kt < 6; ++kt) {
            const half8 b0 = *(const half8*)&xsf[0][kt][lane][0];
            const half8 b1 = *(const half8*)&xsf[1][kt][lane][0];
            #pragma unroll
            for (int g = 0; g < 4; ++g) {
                acc[g][0] = __builtin_amdgcn_mfma_f32_16x16x32_f16(afrag[g][kt], b0, acc[g][0], 0, 0, 0);
                acc[g][1] = __builtin_amdgcn_mfma_f32_16x16x32_f16(afrag[g][kt], b1, acc[g][1], 0, 0, 0);
            }
        }
        #pragma unroll
        for (int ni = 0; ni < 2; ++ni)
            #pragma unroll
            for (int j = 0; j < 4; ++j) {
                const float iv = fsig (acc[0][ni][j] + bfr[0][j]);
                const float fv = fsig (acc[1][ni][j] + bfr[1][j]);
                const float ov = fsig (acc[2][ni][j] + bfr[2][j]);
                const float gv = ftanh(acc[3][ni][j] + bfr[3][j]);
                const int hcr = cg * 16 + l4 * 4 + j; const int wcl = ni * 16 + l15;
                fbuf[hcr][wcl] = fv; pbuf[hcr][wcl] = iv * gv; obuf[hcr][wcl] = ov;
            }
        __syncthreads();
        if (tid < 64) {
            float c = cstate;
            #pragma unroll
            for (int w = 0; w < WC; w += 4) {
                float4 hv;
                #pragma unroll
                for (int e = 0; e < 4; ++e) {
                    c = fmaf(fbuf[tid][w + e], c, pbuf[tid][w + e]);
                    (&hv.x)[e] = obuf[tid][w + e] * ftanh(c);
                }
                *(float4*)(outrow + w0 + w) = hv;
            }
            cstate = c;
        } else if (ck < 3) stage_chunk_fb(xb, h, w0 + WC, xsf, tid - 64, 192);
        __syncthreads();
    }
}

extern "C" void kernel_launch(void* const* d_in, const int* in_sizes, int n_in,
                              void* d_out, int out_size, void* d_ws, size_t ws_size,
                              hipStream_t stream) {
    const float* x    = (const float*)d_in[0];
    const float* wgt  = (const float*)d_in[1];
    const float* bias = (const float*)d_in[2];
    float* out = (float*)d_out;

    if (ws_size >= (size_t)3 * NPLN * sizeof(_Float16)) {
        _Float16* fpl = (_Float16*)d_ws;
        _Float16* ppl = fpl + NPLN;
        _Float16* opl = ppl + NPLN;
        gates_k<<<NB * NH, 256, 0, stream>>>(x, wgt, bias, fpl, ppl, opl);
        scan_k<<<NB * NH / 4, 256, 0, stream>>>(fpl, ppl, opl, out);
    } else {
        rowlstm_fb<<<NB * NH, 256, 0, stream>>>(x, wgt, bias, out);
    }
}

// Round 10
// 224.314 us; speedup vs baseline: 1.4158x; 1.1694x over previous
//
#include <hip/hip_runtime.h>

// RowLSTM v9:
//  K1 gates_k: as v7 (f16 MFMA conv -> f,p,o f16 planes) + ONE change: 2 h-rows
//     per block (grid 1024) to amortize the weight-fragment prologue and halve
//     per-block fixed stalls.
//  K2 scan_k: REPLACED with 4-segment parallel scan per row:
//     c_w = A_w*c0 + B_w (A=prod f, B=scan with c0=0). 4 waves = 4 segments of
//     32 w; one barrier; <=3-step LDS combine; seeded replay with o*tanh(c).
//   x: [B=16, C=64, H=128, W=128] fp32; conv_w: [O=256, C=64, kH=3]; conv_b: [256]
//   out: [B, Hc=64, H, W] fp32.  Gate planes: [B, H, W, Hc] f16.

#define NB   16
#define NC   64
#define NH   128
#define NW   128
#define NHC  64
#define NK   192
#define NPLN (NB * NH * NW * NHC)

typedef _Float16 half4 __attribute__((ext_vector_type(4)));
typedef _Float16 half8 __attribute__((ext_vector_type(8)));
typedef float    f32x4 __attribute__((ext_vector_type(4)));

__device__ __forceinline__ float frcp(float x)  { return __builtin_amdgcn_rcpf(x); }
__device__ __forceinline__ float fsig(float x)  { return frcp(1.f + __expf(-x)); }
__device__ __forceinline__ float ftanh(float x) { return 1.f - 2.f * frcp(__expf(2.f * x) + 1.f); }

// ================= K1: conv gates (2 h per block) =================
#define NIP 3088   // halfs per ni plane: 6*64*8 + 16 pad

__global__ __launch_bounds__(256, 2) void gates_k(
    const float* __restrict__ x,
    const float* __restrict__ wgt,
    const float* __restrict__ bias,
    _Float16* __restrict__ fpl,
    _Float16* __restrict__ ppl,
    _Float16* __restrict__ opl)
{
    __shared__ _Float16 xsf[8 * NIP];   // 49.4 KB

    const int tid  = threadIdx.x;
    const int cg   = tid >> 6;
    const int lane = tid & 63;
    const int l15  = lane & 15;
    const int l4   = lane >> 4;

    int bid = blockIdx.x;                       // XCD swizzle (1024 % 8 == 0)
    bid = (bid & 7) * (1024 / 8) + (bid >> 3);
    const int b  = bid >> 6;
    const int h0 = (bid & 63) * 2;

    const float* xb = x + (size_t)b * NC * NH * NW;

    // ---- prologue (amortized over 2 h): A fragments + bias ----
    half8 afrag[4][6];
    #pragma unroll
    for (int g = 0; g < 4; ++g) {
        const float* wo = wgt + (size_t)(g * 64 + cg * 16 + l15) * NK;
        #pragma unroll
        for (int kt = 0; kt < 6; ++kt) {
            const float4 v0 = *(const float4*)(wo + kt * 32 + l4 * 8);
            const float4 v1 = *(const float4*)(wo + kt * 32 + l4 * 8 + 4);
            half8 a;
            a[0] = (_Float16)v0.x; a[1] = (_Float16)v0.y;
            a[2] = (_Float16)v0.z; a[3] = (_Float16)v0.w;
            a[4] = (_Float16)v1.x; a[5] = (_Float16)v1.y;
            a[6] = (_Float16)v1.z; a[7] = (_Float16)v1.w;
            afrag[g][kt] = a;
        }
    }
    float bfr[4][4];
    #pragma unroll
    for (int g = 0; g < 4; ++g)
        #pragma unroll
        for (int j = 0; j < 4; ++j)
            bfr[g][j] = bias[g * 64 + cg * 16 + l4 * 4 + j];

    for (int hh = 0; hh < 2; ++hh) {
        const int h = h0 + hh;

        // ---- stage full row (192 k x 128 w) ----
        for (int t = tid; t < 1536; t += 256) {
            const int kq  = t >> 5;
            const int wq  = t & 31;
            const int k0  = kq * 4;
            const int w0g = wq * 4;
            float4 v[4];
            #pragma unroll
            for (int dk = 0; dk < 4; ++dk) {
                const int k  = k0 + dk;
                const int c  = k / 3;
                const int kh = k - 3 * c;
                const int r  = h - 2 + kh;
                v[dk] = (r >= 0) ? *(const float4*)(xb + ((size_t)c * NH + r) * NW + w0g)
                                 : make_float4(0.f, 0.f, 0.f, 0.f);
            }
            const int kt = k0 >> 5;
            const int j0 = k0 & 7;
            #pragma unroll
            for (int dw = 0; dw < 4; ++dw) {
                const int w  = w0g + dw;
                const int ni = w >> 4;
                const int L  = ((k0 & 31) >> 3) * 16 + (w & 15);
                half4 hv;
                hv[0] = (_Float16)(&v[0].x)[dw];
                hv[1] = (_Float16)(&v[1].x)[dw];
                hv[2] = (_Float16)(&v[2].x)[dw];
                hv[3] = (_Float16)(&v[3].x)[dw];
                *(half4*)&xsf[ni * NIP + kt * 512 + L * 8 + j0] = hv;
            }
        }
        __syncthreads();

        // ---- 4 passes of 2 ni: MFMA + activation + stores ----
        #pragma unroll
        for (int pr = 0; pr < 4; ++pr) {
            f32x4 acc[4][2];
            #pragma unroll
            for (int g = 0; g < 4; ++g) {
                acc[g][0] = (f32x4){0.f, 0.f, 0.f, 0.f};
                acc[g][1] = (f32x4){0.f, 0.f, 0.f, 0.f};
            }
            #pragma unroll
            for (int kt = 0; kt < 6; ++kt) {
                const half8 b0 = *(const half8*)&xsf[(pr * 2 + 0) * NIP + kt * 512 + lane * 8];
                const half8 b1 = *(const half8*)&xsf[(pr * 2 + 1) * NIP + kt * 512 + lane * 8];
                #pragma unroll
                for (int g = 0; g < 4; ++g) {
                    acc[g][0] = __builtin_amdgcn_mfma_f32_16x16x32_f16(afrag[g][kt], b0, acc[g][0], 0, 0, 0);
                    acc[g][1] = __builtin_amdgcn_mfma_f32_16x16x32_f16(afrag[g][kt], b1, acc[g][1], 0, 0, 0);
                }
            }
            #pragma unroll
            for (int q = 0; q < 2; ++q) {
                const int w   = (pr * 2 + q) * 16 + l15;
                const int hc0 = cg * 16 + l4 * 4;
                half4 f4, p4, o4;
                #pragma unroll
                for (int j = 0; j < 4; ++j) {
                    const float iv = fsig (acc[0][q][j] + bfr[0][j]);
                    const float fv = fsig (acc[1][q][j] + bfr[1][j]);
                    const float ov = fsig (acc[2][q][j] + bfr[2][j]);
                    const float gv = ftanh(acc[3][q][j] + bfr[3][j]);
                    f4[j] = (_Float16)fv;
                    p4[j] = (_Float16)(iv * gv);
                    o4[j] = (_Float16)ov;
                }
                const size_t sb = (((size_t)(b * NH + h) * NW) + w) * NHC + hc0;
                *(half4*)(fpl + sb) = f4;
                *(half4*)(ppl + sb) = p4;
                *(half4*)(opl + sb) = o4;
            }
        }
        __syncthreads();   // xsf reused by next hh
    }
}

// ================= K2: segmented parallel scan =================
// Block = one (b,h) row; wave wv owns w-segment [wv*32, wv*32+32); lane = hc.
// Phase 1: A = prod f, B = scan(p; c0=0), f/p held in registers.
// Combine: c0(wv) = fold of previous segments' (A,B) via LDS (<=3 fma).
// Phase 3: seeded replay, h = o * tanh(c); wave-private LDS bounce for stores.
__global__ __launch_bounds__(256, 4) void scan_k(
    const _Float16* __restrict__ fpl,
    const _Float16* __restrict__ ppl,
    const _Float16* __restrict__ opl,
    float* __restrict__ out)
{
    __shared__ float AB[4][NHC][2];      // 2 KB
    __shared__ float hbuf[4][NHC][33];   // 33.8 KB

    const int tid  = threadIdx.x;
    const int wv   = tid >> 6;
    const int lane = tid & 63;
    const int row  = blockIdx.x;
    const int b    = row >> 7;
    const int h    = row & (NH - 1);
    const int w0   = wv * 32;

    const size_t gbase = (((size_t)(b * NH + h) * NW) + w0) * NHC + lane;

    // ---- phase 1: load f,p; compute segment (A,B) ----
    _Float16 fu[32], pu[32];
    #pragma unroll
    for (int s = 0; s < 32; ++s) {
        fu[s] = fpl[gbase + (size_t)s * NHC];
        pu[s] = ppl[gbase + (size_t)s * NHC];
    }
    float A = 1.f, Bv = 0.f;
    #pragma unroll
    for (int s = 0; s < 32; ++s) {
        const float f = (float)fu[s];
        A  = A * f;
        Bv = fmaf(f, Bv, (float)pu[s]);
    }
    AB[wv][lane][0] = A;
    AB[wv][lane][1] = Bv;
    __syncthreads();

    // ---- combine: incoming c0 for this segment ----
    float c = 0.f;
    for (int s = 0; s < wv; ++s)              // wave-uniform trip count
        c = fmaf(AB[s][lane][0], c, AB[s][lane][1]);

    // ---- phase 3: load o; seeded replay ----
    _Float16 ou[32];
    #pragma unroll
    for (int s = 0; s < 32; ++s)
        ou[s] = opl[gbase + (size_t)s * NHC];

    #pragma unroll
    for (int s = 0; s < 32; ++s) {
        c = fmaf((float)fu[s], c, (float)pu[s]);
        hbuf[wv][lane][s] = (float)ou[s] * ftanh(c);
    }

    // ---- flush: 32 coalesced dword stores (wave-private, no barrier) ----
    const int wl = lane & 31;
    const int hq = lane >> 5;
    #pragma unroll
    for (int it = 0; it < 32; ++it) {
        const int hc = it * 2 + hq;
        out[(((size_t)b * NHC + hc) * NH + h) * NW + w0 + wl] = hbuf[wv][hc][wl];
    }
}

// ================= fallback (v3b fused, known-pass) =================
#define WC 32
#define GP (WC + 2)
#define NQ (48 * WC)
__device__ __forceinline__ void stage_chunk_fb(const float* __restrict__ xb, int h, int w0,
                                               _Float16 (*xsf)[6][64][8], int qstart, int qstep) {
    for (int q = qstart; q < NQ; q += qstep) {
        const int k4 = q >> 5; const int w = q & 31;
        const int ni = w >> 4; const int kt = k4 >> 3;
        const int L = ((k4 >> 1) & 3) * 16 + (w & 15);
        const int j0 = (k4 & 1) * 4;
        half4 hv;
        #pragma unroll
        for (int e = 0; e < 4; ++e) {
            const int k = k4 * 4 + e; const int c = k / 3;
            const int kh = k - 3 * c; const int r = h - 2 + kh;
            float v = 0.f;
            if (r >= 0) v = xb[((size_t)c * NH + r) * NW + w0 + w];
            hv[e] = (_Float16)v;
        }
        *(half4*)&xsf[ni][kt][L][j0] = hv;
    }
}
__global__ __launch_bounds__(256, 2) void rowlstm_fb(
    const float* __restrict__ x, const float* __restrict__ wgt,
    const float* __restrict__ bias, float* __restrict__ out)
{
    __shared__ _Float16 xsf[2][6][64][8];
    __shared__ float fbuf[NHC][GP]; __shared__ float pbuf[NHC][GP]; __shared__ float obuf[NHC][GP];
    const int tid = threadIdx.x; const int cg = tid >> 6;
    const int lane = tid & 63; const int l15 = lane & 15; const int l4 = lane >> 4;
    int bid = blockIdx.x; bid = (bid & 7) * (NB * NH / 8) + (bid >> 3);
    const int b = bid >> 7; const int h = bid & (NH - 1);
    const float* xb = x + (size_t)b * NC * NH * NW;
    half8 afrag[4][6];
    #pragma unroll
    for (int g = 0; g < 4; ++g) {
        const float* wo = wgt + (size_t)(g * 64 + cg * 16 + l15) * NK;
        #pragma unroll
        for (int kt = 0; kt < 6; ++kt) {
            const float4 v0 = *(const float4*)(wo + kt * 32 + l4 * 8);
            const float4 v1 = *(const float4*)(wo + kt * 32 + l4 * 8 + 4);
            half8 a;
            a[0]=(_Float16)v0.x;a[1]=(_Float16)v0.y;a[2]=(_Float16)v0.z;a[3]=(_Float16)v0.w;
            a[4]=(_Float16)v1.x;a[5]=(_Float16)v1.y;a[6]=(_Float16)v1.z;a[7]=(_Float16)v1.w;
            afrag[g][kt] = a;
        }
    }
    float bfr[4][4];
    #pragma unroll
    for (int g = 0; g < 4; ++g)
        #pragma unroll
        for (int j = 0; j < 4; ++j) bfr[g][j] = bias[g * 64 + cg * 16 + l4 * 4 + j];
    float cstate = 0.f;
    float* outrow = out + (((size_t)b * NHC + tid) * NH + h) * NW;
    stage_chunk_fb(xb, h, 0, xsf, tid, 256);
    __syncthreads();
    for (int ck = 0; ck < 4; ++ck) {
        const int w0 = ck * WC;
        f32x4 acc[4][2];
        #pragma unroll
        for (int g = 0; g < 4; ++g) { acc[g][0]=(f32x4){0,0,0,0}; acc[g][1]=(f32x4){0,0,0,0}; }
        #pragma unroll
        for (int kt = 0; kt < 6; ++kt) {
            const half8 b0 = *(const half8*)&xsf[0][kt][lane][0];
            const half8 b1 = *(const half8*)&xsf[1][kt][lane][0];
            #pragma unroll
            for (int g = 0; g < 4; ++g) {
                acc[g][0] = __builtin_amdgcn_mfma_f32_16x16x32_f16(afrag[g][kt], b0, acc[g][0], 0, 0, 0);
                acc[g][1] = __builtin_amdgcn_mfma_f32_16x16x32_f16(afrag[g][kt], b1, acc[g][1], 0, 0, 0);
            }
        }
        #pragma unroll
        for (int ni = 0; ni < 2; ++ni)
            #pragma unroll
            for (int j = 0; j < 4; ++j) {
                const float iv = fsig (acc[0][ni][j] + bfr[0][j]);
                const float fv = fsig (acc[1][ni][j] + bfr[1][j]);
                const float ov = fsig (acc[2][ni][j] + bfr[2][j]);
                const float gv = ftanh(acc[3][ni][j] + bfr[3][j]);
                const int hcr = cg * 16 + l4 * 4 + j; const int wcl = ni * 16 + l15;
                fbuf[hcr][wcl] = fv; pbuf[hcr][wcl] = iv * gv; obuf[hcr][wcl] = ov;
            }
        __syncthreads();
        if (tid < 64) {
            float c = cstate;
            #pragma unroll
            for (int w = 0; w < WC; w += 4) {
                float4 hv;
                #pragma unroll
                for (int e = 0; e < 4; ++e) {
                    c = fmaf(fbuf[tid][w + e], c, pbuf[tid][w + e]);
                    (&hv.x)[e] = obuf[tid][w + e] * ftanh(c);
                }
                *(float4*)(outrow + w0 + w) = hv;
            }
            cstate = c;
        } else if (ck < 3) stage_chunk_fb(xb, h, w0 + WC, xsf, tid - 64, 192);
        __syncthreads();
    }
}

extern "C" void kernel_launch(void* const* d_in, const int* in_sizes, int n_in,
                              void* d_out, int out_size, void* d_ws, size_t ws_size,
                              hipStream_t stream) {
    const float* x    = (const float*)d_in[0];
    const float* wgt  = (const float*)d_in[1];
    const float* bias = (const float*)d_in[2];
    float* out = (float*)d_out;

    if (ws_size >= (size_t)3 * NPLN * sizeof(_Float16)) {
        _Float16* fpl = (_Float16*)d_ws;
        _Float16* ppl = fpl + NPLN;
        _Float16* opl = ppl + NPLN;
        gates_k<<<1024, 256, 0, stream>>>(x, wgt, bias, fpl, ppl, opl);
        scan_k<<<NB * NH, 256, 0, stream>>>(fpl, ppl, opl, out);
    } else {
        rowlstm_fb<<<NB * NH, 256, 0, stream>>>(x, wgt, bias, out);
    }
}